// Round 3
// baseline (224.443 us; speedup 1.0000x reference)
//
#include <hip/hip_runtime.h>

// ---------------------------------------------------------------------------
// 2-layer tanh RNN, H=4, I=2, packed sequences. 4 lanes per batch element.
// State transform: r = (1 - h)/2  =>  r' = rcp(1 + exp2(C + V·r)),
// V = -2*K*W, K = 2*log2(e). States free-run past len; layer-2 output is
// snapshotted at tt == len (off the recurrence critical path).
// Matvecs are single-accumulator v_fmac chains with quad_perm DPP operands
// (GCNDPPCombine folds single-use mov_dpp into v_fmac_f32_dpp).
// Issue-bound at ~80% SIMD busy (1 wave/CU) -> minimize instructions/step.
// ---------------------------------------------------------------------------

#define QP1 0xB1  // quad_perm [1,0,3,2]  (xor 1)
#define QP2 0x4E  // quad_perm [2,3,0,1]  (xor 2)
#define QP3 0x1B  // quad_perm [3,2,1,0]  (xor 3)

template<int C>
__device__ __forceinline__ float qp(float x) {
    return __int_as_float(__builtin_amdgcn_mov_dpp(__float_as_int(x), C, 0xF, 0xF, true));
}

// Pack tokens (int 0/1) into bitmasks, bit t%64 of word t/64 per row.
__global__ __launch_bounds__(1024) void pack_kernel(const int* __restrict__ toks,
                                                    unsigned long long* __restrict__ packed) {
    const int lane = threadIdx.x & 63;
    const int wid  = threadIdx.x >> 6;
    const long long tb = (long long)blockIdx.x * 4096 + wid * 256;
    unsigned long long w0 = __ballot(toks[tb +   0 + lane] != 0);
    unsigned long long w1 = __ballot(toks[tb +  64 + lane] != 0);
    unsigned long long w2 = __ballot(toks[tb + 128 + lane] != 0);
    unsigned long long w3 = __ballot(toks[tb + 192 + lane] != 0);
    if (lane < 4) {
        unsigned long long v = lane == 0 ? w0 : lane == 1 ? w1 : lane == 2 ? w2 : w3;
        packed[(tb >> 6) + lane] = v;
    }
}

// Iteration tt = t0+ss computes r1(tt) [L1] and r2(tt-1) [L2, uses old r1,r2].
// FIRST discards the pipeline-fill L2 output at tt==0.
#define STEP(ss, FIRST)                                                   \
  {                                                                       \
    float z1 = ((w >> (ss)) & 1u) ? C1 : C0;                              \
    z1 += r1 * v0a;                                                       \
    z1 += qp<QP1>(r1) * v0b;                                              \
    z1 += qp<QP2>(r1) * v0c;                                              \
    z1 += qp<QP3>(r1) * v0d;                                              \
    float zA = fmaf(r1, vAa, C2);                                         \
    zA += qp<QP1>(r1) * vAb;                                              \
    zA += qp<QP2>(r1) * vAc;                                              \
    zA += qp<QP3>(r1) * vAd;                                              \
    float zB = r2 * vHa;                                                  \
    zB += qp<QP1>(r2) * vHb;                                              \
    zB += qp<QP2>(r2) * vHc;                                              \
    zB += qp<QP3>(r2) * vHd;                                              \
    float e1  = __builtin_amdgcn_exp2f(z1);                               \
    float r1n = __builtin_amdgcn_rcpf(e1 + 1.0f);                         \
    float e2  = __builtin_amdgcn_exp2f(zA + zB);                          \
    float r2n = __builtin_amdgcn_rcpf(e2 + 1.0f);                         \
    save = ((ss) == lmt) ? r2n : save;                                    \
    r1 = r1n;                                                             \
    r2 = (FIRST) ? r2i : r2n;                                             \
  }

__global__ __launch_bounds__(64) void rnn_kernel(
    const unsigned* __restrict__ packed,   // [B][T/32]
    const int* __restrict__ lengths,
    const float* __restrict__ W_ih0, const float* __restrict__ W_hh0,
    const float* __restrict__ b_ih0, const float* __restrict__ b_hh0,
    const float* __restrict__ W_ih1, const float* __restrict__ W_hh1,
    const float* __restrict__ b_ih1, const float* __restrict__ b_hh1,
    const float* __restrict__ h0,
    float* __restrict__ out, int T)
{
    const int lane = threadIdx.x;
    const int q    = lane >> 2;
    const int i    = lane & 3;
    const int b    = blockIdx.x * 16 + q;
    const int Tw   = T >> 5;

    const float K  = 2.8853900817779268f;   // 2*log2(e)
    const float NK = -2.0f * K;

    float rs0 = W_hh0[i*4+0] + W_hh0[i*4+1] + W_hh0[i*4+2] + W_hh0[i*4+3];
    float cb0 = b_ih0[i] + b_hh0[i] + rs0;
    float C0  = K * (W_ih0[i*2+0] + cb0);
    float C1  = K * (W_ih0[i*2+1] + cb0);
    float v0a = NK * W_hh0[i*4 + i],     v0b = NK * W_hh0[i*4 + (i^1)];
    float v0c = NK * W_hh0[i*4 + (i^2)], v0d = NK * W_hh0[i*4 + (i^3)];

    float rsA = W_ih1[i*4+0] + W_ih1[i*4+1] + W_ih1[i*4+2] + W_ih1[i*4+3];
    float rsH = W_hh1[i*4+0] + W_hh1[i*4+1] + W_hh1[i*4+2] + W_hh1[i*4+3];
    float C2  = K * (b_ih1[i] + b_hh1[i] + rsA + rsH);
    float vAa = NK * W_ih1[i*4 + i],     vAb = NK * W_ih1[i*4 + (i^1)];
    float vAc = NK * W_ih1[i*4 + (i^2)], vAd = NK * W_ih1[i*4 + (i^3)];
    float vHa = NK * W_hh1[i*4 + i],     vHb = NK * W_hh1[i*4 + (i^1)];
    float vHc = NK * W_hh1[i*4 + (i^2)], vHd = NK * W_hh1[i*4 + (i^3)];

    float r1   = fmaf(-0.5f, h0[i],     0.5f);   // r = (1-h)/2
    float r2i  = fmaf(-0.5f, h0[4 + i], 0.5f);
    float r2   = r2i;
    float save = r2i;
    const int len = lengths[b];

    // wave-wide max length -> uniform loop bound
    int wmax = len;
    #pragma unroll
    for (int off = 32; off; off >>= 1) {
        int o = __shfl_xor(wmax, off, 64);
        wmax = wmax > o ? wmax : o;
    }
    wmax = __builtin_amdgcn_readfirstlane(wmax);

    const unsigned* row = packed + (size_t)b * Tw;
    unsigned wcur  = row[0];
    unsigned wnext = row[1 < Tw ? 1 : Tw - 1];

    int lmt = len;   // len - t0

    // block 0 (iterations 0..31); ss==0 is the pipeline-fill step whose
    // throwaway L2 output is replaced by the initial state (FIRST=true).
    {
        unsigned w = wcur;
        wcur  = wnext;
        wnext = row[2 < Tw ? 2 : Tw - 1];
        STEP(0, true)
        #pragma unroll
        for (int s = 1; s < 32; ++s) {
            STEP(s, false)
        }
        lmt -= 32;
    }
    for (int t0 = 32; t0 <= wmax; t0 += 32) {
        unsigned w = wcur;
        wcur = wnext;
        int nidx = (t0 >> 5) + 2;
        wnext = row[nidx < Tw ? nidx : Tw - 1];
        #pragma unroll
        for (int s = 0; s < 32; ++s) {
            STEP(s, false)
        }
        lmt -= 32;
    }

    out[b * 4 + i] = fmaf(-2.0f, save, 1.0f);
}

extern "C" void kernel_launch(void* const* d_in, const int* in_sizes, int n_in,
                              void* d_out, int out_size, void* d_ws, size_t ws_size,
                              hipStream_t stream) {
    const int*   tokens  = (const int*)d_in[0];
    const int*   lengths = (const int*)d_in[1];
    const float* W_ih0   = (const float*)d_in[2];
    const float* W_hh0   = (const float*)d_in[3];
    const float* b_ih0   = (const float*)d_in[4];
    const float* b_hh0   = (const float*)d_in[5];
    const float* W_ih1   = (const float*)d_in[6];
    const float* W_hh1   = (const float*)d_in[7];
    const float* b_ih1   = (const float*)d_in[8];
    const float* b_hh1   = (const float*)d_in[9];
    const float* h0      = (const float*)d_in[10];
    float* out = (float*)d_out;

    const int B = in_sizes[1];
    const int T = in_sizes[0] / B;

    unsigned long long* packed = (unsigned long long*)d_ws;  // B*T/8 bytes

    pack_kernel<<<(B * T) / 4096, 1024, 0, stream>>>(tokens, packed);
    rnn_kernel<<<B / 16, 64, 0, stream>>>((const unsigned*)packed, lengths,
        W_ih0, W_hh0, b_ih0, b_hh0, W_ih1, W_hh1, b_ih1, b_hh1, h0, out, T);
}

// Round 4
// 185.323 us; speedup vs baseline: 1.2111x; 1.2111x over previous
//
#include <hip/hip_runtime.h>

// ---------------------------------------------------------------------------
// 2-layer tanh RNN, H=4, I=2, packed sequences.
// 8 lanes per batch element: lanes 0-3 run layer 1, lanes 4-7 run layer 2
// (1-step lag makes them independent). One row_shr:4 DPP per step passes
// r1(t-1) from the L1 quad to the L2 quad; both halves execute an identical
// z = c + sum w*qp(s) + sum u*qp(o) stream (u=0 on L1 lanes).
// State transform r = (1-h)/2 => r' = rcp(1 + exp2(C + V.r)), V = -2K W,
// K = 2 log2 e. 512 waves -> 2 SIMDs/CU busy; ~19 instr (2 trans)/step/wave.
// ---------------------------------------------------------------------------

#define QP1 0xB1   // quad_perm [1,0,3,2]  (xor 1)
#define QP2 0x4E   // quad_perm [2,3,0,1]  (xor 2)
#define QP3 0x1B   // quad_perm [3,2,1,0]  (xor 3)
#define RSHR4 0x114 // row_shr:4  (lane i reads lane i-4 within 16-lane row)

template<int C>
__device__ __forceinline__ float qp(float x) {
    return __int_as_float(__builtin_amdgcn_mov_dpp(__float_as_int(x), C, 0xF, 0xF, true));
}

// Pack tokens (int 0/1) into bitmasks, bit t%64 of word t/64 per row.
__global__ __launch_bounds__(1024) void pack_kernel(const int* __restrict__ toks,
                                                    unsigned long long* __restrict__ packed) {
    const int lane = threadIdx.x & 63;
    const int wid  = threadIdx.x >> 6;
    const long long tb = (long long)blockIdx.x * 4096 + wid * 256;
    unsigned long long w0 = __ballot(toks[tb +   0 + lane] != 0);
    unsigned long long w1 = __ballot(toks[tb +  64 + lane] != 0);
    unsigned long long w2 = __ballot(toks[tb + 128 + lane] != 0);
    unsigned long long w3 = __ballot(toks[tb + 192 + lane] != 0);
    if (lane < 4) {
        unsigned long long v = lane == 0 ? w0 : lane == 1 ? w1 : lane == 2 ? w2 : w3;
        packed[(tb >> 6) + lane] = v;
    }
}

// Iteration tt = t0+ss: L1 lanes produce r1(tt), L2 lanes produce r2(tt-1).
#define STEP(ss, FIRST)                                                   \
  {                                                                       \
    float o  = __int_as_float(__builtin_amdgcn_mov_dpp(                   \
                   __float_as_int(s), RSHR4, 0xF, 0xF, true));            \
    float c  = (w & (1u << (ss))) ? cB : cA;                              \
    float zA = fmaf(s, wa, c);                                            \
    zA = fmaf(qp<QP1>(s), wb, zA);                                        \
    zA = fmaf(qp<QP2>(s), wc, zA);                                        \
    zA = fmaf(qp<QP3>(s), wd, zA);                                        \
    float zB = o * ua;                                                    \
    zB = fmaf(qp<QP1>(o), ub, zB);                                        \
    zB = fmaf(qp<QP2>(o), uc, zB);                                        \
    zB = fmaf(qp<QP3>(o), ud, zB);                                        \
    float e = __builtin_amdgcn_exp2f(zA + zB);                            \
    float r = __builtin_amdgcn_rcpf(e + 1.0f);                            \
    save = ((ss) == lmt) ? r : save;                                      \
    s = (FIRST) ? (isL2 ? r2i : r) : r;                                   \
  }

__global__ __launch_bounds__(64) void rnn_kernel(
    const unsigned* __restrict__ packed,   // [B][T/32]
    const int* __restrict__ lengths,
    const float* __restrict__ W_ih0, const float* __restrict__ W_hh0,
    const float* __restrict__ b_ih0, const float* __restrict__ b_hh0,
    const float* __restrict__ W_ih1, const float* __restrict__ W_hh1,
    const float* __restrict__ b_ih1, const float* __restrict__ b_hh1,
    const float* __restrict__ h0,
    float* __restrict__ out, int T)
{
    const int lane = threadIdx.x;      // 0..63
    const int g    = lane >> 3;        // element within wave, 0..7
    const int hh   = lane & 7;
    const bool isL2 = (hh & 4) != 0;   // lanes 4-7 of each octet = layer 2
    const int i    = hh & 3;           // component 0..3
    const int b    = blockIdx.x * 8 + g;
    const int Tw   = T >> 5;

    const float K  = 2.8853900817779268f;   // 2*log2(e)
    const float NK = -2.0f * K;

    // layer-1 constants (token-selected additive term)
    float rs0 = W_hh0[i*4+0] + W_hh0[i*4+1] + W_hh0[i*4+2] + W_hh0[i*4+3];
    float cb0 = b_ih0[i] + b_hh0[i] + rs0;
    float C0  = K * (W_ih0[i*2+0] + cb0);
    float C1  = K * (W_ih0[i*2+1] + cb0);
    // layer-2 constant
    float rsA = W_ih1[i*4+0] + W_ih1[i*4+1] + W_ih1[i*4+2] + W_ih1[i*4+3];
    float rsH = W_hh1[i*4+0] + W_hh1[i*4+1] + W_hh1[i*4+2] + W_hh1[i*4+3];
    float C2  = K * (b_ih1[i] + b_hh1[i] + rsA + rsH);

    float wa, wb, wc, wd, ua, ub, uc, ud, cA, cB, s;
    if (!isL2) {
        wa = NK * W_hh0[i*4 + i];     wb = NK * W_hh0[i*4 + (i^1)];
        wc = NK * W_hh0[i*4 + (i^2)]; wd = NK * W_hh0[i*4 + (i^3)];
        ua = ub = uc = ud = 0.0f;
        cA = C0; cB = C1;
        s  = fmaf(-0.5f, h0[i], 0.5f);
    } else {
        wa = NK * W_hh1[i*4 + i];     wb = NK * W_hh1[i*4 + (i^1)];
        wc = NK * W_hh1[i*4 + (i^2)]; wd = NK * W_hh1[i*4 + (i^3)];
        ua = NK * W_ih1[i*4 + i];     ub = NK * W_ih1[i*4 + (i^1)];
        uc = NK * W_ih1[i*4 + (i^2)]; ud = NK * W_ih1[i*4 + (i^3)];
        cA = cB = C2;
        s  = fmaf(-0.5f, h0[4 + i], 0.5f);
    }
    const float r2i = fmaf(-0.5f, h0[4 + i], 0.5f);
    float save = r2i;
    const int len = lengths[b];

    // wave-wide max length (len uniform within each octet) -> uniform bound
    int wmax = len;
    #pragma unroll
    for (int off = 8; off <= 32; off <<= 1) {
        int o2 = __shfl_xor(wmax, off, 64);
        wmax = wmax > o2 ? wmax : o2;
    }
    wmax = __builtin_amdgcn_readfirstlane(wmax);

    const unsigned* row = packed + (size_t)b * Tw;
    unsigned wcur  = row[0];
    unsigned wnext = row[1 < Tw ? 1 : Tw - 1];

    int lmt = len;   // len - t0

    // block 0: ss==0 is the pipeline-fill step; its throwaway L2 output is
    // replaced by the initial layer-2 state (FIRST=true).
    {
        unsigned w = wcur;
        wcur  = wnext;
        wnext = row[2 < Tw ? 2 : Tw - 1];
        STEP(0, true)
        #pragma unroll
        for (int ss = 1; ss < 32; ++ss) {
            STEP(ss, false)
        }
        lmt -= 32;
    }
    for (int t0 = 32; t0 <= wmax; t0 += 32) {
        unsigned w = wcur;
        wcur = wnext;
        int nidx = (t0 >> 5) + 2;
        wnext = row[nidx < Tw ? nidx : Tw - 1];
        #pragma unroll
        for (int ss = 0; ss < 32; ++ss) {
            STEP(ss, false)
        }
        lmt -= 32;
    }

    if (isL2) out[b * 4 + i] = fmaf(-2.0f, save, 1.0f);
}

extern "C" void kernel_launch(void* const* d_in, const int* in_sizes, int n_in,
                              void* d_out, int out_size, void* d_ws, size_t ws_size,
                              hipStream_t stream) {
    const int*   tokens  = (const int*)d_in[0];
    const int*   lengths = (const int*)d_in[1];
    const float* W_ih0   = (const float*)d_in[2];
    const float* W_hh0   = (const float*)d_in[3];
    const float* b_ih0   = (const float*)d_in[4];
    const float* b_hh0   = (const float*)d_in[5];
    const float* W_ih1   = (const float*)d_in[6];
    const float* W_hh1   = (const float*)d_in[7];
    const float* b_ih1   = (const float*)d_in[8];
    const float* b_hh1   = (const float*)d_in[9];
    const float* h0      = (const float*)d_in[10];
    float* out = (float*)d_out;

    const int B = in_sizes[1];
    const int T = in_sizes[0] / B;

    unsigned long long* packed = (unsigned long long*)d_ws;  // B*T/8 bytes

    pack_kernel<<<(B * T) / 4096, 1024, 0, stream>>>(tokens, packed);
    rnn_kernel<<<B / 8, 64, 0, stream>>>((const unsigned*)packed, lengths,
        W_ih0, W_hh0, b_ih0, b_hh0, W_ih1, W_hh1, b_ih1, b_hh1, h0, out, T);
}

// Round 5
// 181.434 us; speedup vs baseline: 1.2371x; 1.0214x over previous
//
#include <hip/hip_runtime.h>

// ---------------------------------------------------------------------------
// 2-layer tanh RNN, H=4, I=2, packed sequences.
// 8 lanes per batch element: lanes 0-3 = layer 1, lanes 4-7 = layer 2.
// State transform r = (1-h)/2 => r' = rcp(1 + exp2(C + V.r)), V = -2K W,
// K = 2 log2 e.
// DPP-minimized: L1 lanes compute BOTH their own recurrence dot (W_hh0) and
// layer-2's input dot D = U.r1 (U = -2K W_ih1), reusing the same 3 quad_perm
// values. One row_shr:4 (folded into v_add_f32_dpp) passes the finished
// scalar D to the L2 lanes. L2 runs 2 steps behind L1:
//   iter n: L1 -> r1(n),  D(n) = U.r1(n-1),  L2 -> r2(n-2) using D(n-1).
// Iters 0,1 produce garbage r2 (discarded, s2 re-init). Save at ss==len+1.
// DPP-class ops/step: 4 (vs 7 before); plain VALU ~17.
// ---------------------------------------------------------------------------

#define QP1 0xB1    // quad_perm [1,0,3,2]  (xor 1)
#define QP2 0x4E    // quad_perm [2,3,0,1]  (xor 2)
#define QP3 0x1B    // quad_perm [3,2,1,0]  (xor 3)
#define RSHR4 0x114 // row_shr:4

template<int C>
__device__ __forceinline__ float qp(float x) {
    return __int_as_float(__builtin_amdgcn_mov_dpp(__float_as_int(x), C, 0xF, 0xF, true));
}

// Pack tokens (int 0/1) into bitmasks, bit t%64 of word t/64 per row.
__global__ __launch_bounds__(1024) void pack_kernel(const int* __restrict__ toks,
                                                    unsigned long long* __restrict__ packed) {
    const int lane = threadIdx.x & 63;
    const int wid  = threadIdx.x >> 6;
    const long long tb = (long long)blockIdx.x * 4096 + wid * 256;
    unsigned long long w0 = __ballot(toks[tb +   0 + lane] != 0);
    unsigned long long w1 = __ballot(toks[tb +  64 + lane] != 0);
    unsigned long long w2 = __ballot(toks[tb + 128 + lane] != 0);
    unsigned long long w3 = __ballot(toks[tb + 192 + lane] != 0);
    if (lane < 4) {
        unsigned long long v = lane == 0 ? w0 : lane == 1 ? w1 : lane == 2 ? w2 : w3;
        packed[(tb >> 6) + lane] = v;
    }
}

// Iteration tt = t0+ss. FIRST (iters 0,1 only) discards L2's fill output.
#define STEP(ss, FIRST)                                                   \
  {                                                                       \
    float c = (w & (1u << (ss))) ? cB : cA;                               \
    float o = __int_as_float(__builtin_amdgcn_mov_dpp(                    \
                  __float_as_int(D), RSHR4, 0xF, 0xF, true));             \
    float init = c + o;                                                   \
    float x1 = qp<QP1>(s), x2 = qp<QP2>(s), x3 = qp<QP3>(s);              \
    float f1 = fmaf(s, wa, init);                                         \
    f1 = fmaf(x1, wb, f1);                                                \
    float f2 = x2 * wc;                                                   \
    f2 = fmaf(x3, wd, f2);                                                \
    float Dn = s * ua;                                                    \
    Dn = fmaf(x1, ub, Dn);                                                \
    Dn = fmaf(x2, uc, Dn);                                                \
    Dn = fmaf(x3, ud, Dn);                                                \
    float e = __builtin_amdgcn_exp2f(f1 + f2);                            \
    float r = __builtin_amdgcn_rcpf(e + 1.0f);                            \
    save = ((ss) == lmt2) ? r : save;                                     \
    s = (FIRST) ? (isL2 ? r2i : r) : r;                                   \
    D = Dn;                                                               \
  }

__global__ __launch_bounds__(64) void rnn_kernel(
    const unsigned* __restrict__ packed,   // [B][T/32]
    const int* __restrict__ lengths,
    const float* __restrict__ W_ih0, const float* __restrict__ W_hh0,
    const float* __restrict__ b_ih0, const float* __restrict__ b_hh0,
    const float* __restrict__ W_ih1, const float* __restrict__ W_hh1,
    const float* __restrict__ b_ih1, const float* __restrict__ b_hh1,
    const float* __restrict__ h0,
    float* __restrict__ out, int T)
{
    const int lane = threadIdx.x;      // 0..63
    const int g    = lane >> 3;        // element within wave, 0..7
    const int hh   = lane & 7;
    const bool isL2 = (hh & 4) != 0;   // lanes 4-7 of each octet = layer 2
    const int i    = hh & 3;           // component / row 0..3
    const int b    = blockIdx.x * 8 + g;
    const int Tw   = T >> 5;

    const float K  = 2.8853900817779268f;   // 2*log2(e)
    const float NK = -2.0f * K;

    // layer-1 constants (token-selected additive term)
    float rs0 = W_hh0[i*4+0] + W_hh0[i*4+1] + W_hh0[i*4+2] + W_hh0[i*4+3];
    float cb0 = b_ih0[i] + b_hh0[i] + rs0;
    float C0  = K * (W_ih0[i*2+0] + cb0);
    float C1  = K * (W_ih0[i*2+1] + cb0);
    // layer-2 constant (includes both rowsums)
    float rsA = W_ih1[i*4+0] + W_ih1[i*4+1] + W_ih1[i*4+2] + W_ih1[i*4+3];
    float rsH = W_hh1[i*4+0] + W_hh1[i*4+1] + W_hh1[i*4+2] + W_hh1[i*4+3];
    float C2  = K * (b_ih1[i] + b_hh1[i] + rsA + rsH);

    // own-recurrence weights w*, aux-dot weights u* (aux lives on L1 lanes)
    float wa, wb, wc, wd, ua, ub, uc, ud, cA, cB, s;
    if (!isL2) {
        wa = NK * W_hh0[i*4 + i];     wb = NK * W_hh0[i*4 + (i^1)];
        wc = NK * W_hh0[i*4 + (i^2)]; wd = NK * W_hh0[i*4 + (i^3)];
        ua = NK * W_ih1[i*4 + i];     ub = NK * W_ih1[i*4 + (i^1)];
        uc = NK * W_ih1[i*4 + (i^2)]; ud = NK * W_ih1[i*4 + (i^3)];
        cA = C0; cB = C1;
        s  = fmaf(-0.5f, h0[i], 0.5f);
    } else {
        wa = NK * W_hh1[i*4 + i];     wb = NK * W_hh1[i*4 + (i^1)];
        wc = NK * W_hh1[i*4 + (i^2)]; wd = NK * W_hh1[i*4 + (i^3)];
        ua = ub = uc = ud = 0.0f;     // L2's aux-dot = 0 (also feeds the
                                      // row_shr4 wraparound with exact 0)
        cA = cB = C2;
        s  = fmaf(-0.5f, h0[4 + i], 0.5f);
    }
    const float r2i = fmaf(-0.5f, h0[4 + i], 0.5f);
    float save = r2i;
    float D = 0.0f;
    const int len = lengths[b];

    // wave-wide max length (len uniform within each octet) -> uniform bound
    int wmax = len;
    #pragma unroll
    for (int off = 8; off <= 32; off <<= 1) {
        int o2 = __shfl_xor(wmax, off, 64);
        wmax = wmax > o2 ? wmax : o2;
    }
    wmax = __builtin_amdgcn_readfirstlane(wmax);

    const unsigned* row = packed + (size_t)b * Tw;
    unsigned wcur  = row[0];
    unsigned wnext = row[1 < Tw ? 1 : Tw - 1];

    int lmt2 = len + 1;   // L2 emits r2(len-1) at iteration len+1

    // block 0: iters 0,1 are pipeline fill (L2 output discarded)
    {
        unsigned w = wcur;
        wcur  = wnext;
        wnext = row[2 < Tw ? 2 : Tw - 1];
        STEP(0, true)
        STEP(1, true)
        #pragma unroll
        for (int ss = 2; ss < 32; ++ss) {
            STEP(ss, false)
        }
        lmt2 -= 32;
    }
    // need iterations through wmax+1
    for (int t0 = 32; t0 <= wmax + 1; t0 += 32) {
        unsigned w = wcur;
        wcur = wnext;
        int nidx = (t0 >> 5) + 2;
        wnext = row[nidx < Tw ? nidx : Tw - 1];
        #pragma unroll
        for (int ss = 0; ss < 32; ++ss) {
            STEP(ss, false)
        }
        lmt2 -= 32;
    }

    if (isL2) out[b * 4 + i] = fmaf(-2.0f, save, 1.0f);
}

extern "C" void kernel_launch(void* const* d_in, const int* in_sizes, int n_in,
                              void* d_out, int out_size, void* d_ws, size_t ws_size,
                              hipStream_t stream) {
    const int*   tokens  = (const int*)d_in[0];
    const int*   lengths = (const int*)d_in[1];
    const float* W_ih0   = (const float*)d_in[2];
    const float* W_hh0   = (const float*)d_in[3];
    const float* b_ih0   = (const float*)d_in[4];
    const float* b_hh0   = (const float*)d_in[5];
    const float* W_ih1   = (const float*)d_in[6];
    const float* W_hh1   = (const float*)d_in[7];
    const float* b_ih1   = (const float*)d_in[8];
    const float* b_hh1   = (const float*)d_in[9];
    const float* h0      = (const float*)d_in[10];
    float* out = (float*)d_out;

    const int B = in_sizes[1];
    const int T = in_sizes[0] / B;

    unsigned long long* packed = (unsigned long long*)d_ws;  // B*T/8 bytes

    pack_kernel<<<(B * T) / 4096, 1024, 0, stream>>>(tokens, packed);
    rnn_kernel<<<B / 8, 64, 0, stream>>>((const unsigned*)packed, lengths,
        W_ih0, W_hh0, b_ih0, b_hh0, W_ih1, W_hh1, b_ih1, b_hh1, h0, out, T);
}

// Round 7
// 166.999 us; speedup vs baseline: 1.3440x; 1.0864x over previous
//
#include <hip/hip_runtime.h>

// ---------------------------------------------------------------------------
// 2-layer tanh RNN, H=4, I=2, packed sequences.
// 8 lanes per batch element: lanes 0-3 = layer 1, lanes 4-7 = layer 2.
// State transform r = (1-h)/2 => r' = rcp(1 + exp2(C + V.r)), V = -2K W,
// K = 2 log2 e.
// f16-dot2 version: per step each lane packs A=(r_i, r_i^1) via cvt_pkrtz
// (+1 DPP for the partner), gets B=(r_i^2, r_i^3) with ONE 32-bit DPP of A,
// and computes both 4-wide dots (own recurrence + layer-2 input D) as
// 4x v_dot2_f32_f16 (f32 accumulate). C2 is baked into D's base so L2's
// init is just the row_shr4 'o'. f16 weight rounding is compensated by
// adding 0.5*sum(deltas) into the z-constants (centers error at r~0.5).
// Save cmp/cndmask is branch-guarded per 32-block (wave-uniform __any).
// Stream ~15 instr/step (3 DPP-class, 2 trans, 4 dot2) vs 21 before.
// ---------------------------------------------------------------------------

typedef __fp16 h2 __attribute__((ext_vector_type(2)));

#define QP1 0xB1    // quad_perm [1,0,3,2]  (xor 1)
#define QP2 0x4E    // quad_perm [2,3,0,1]  (xor 2)
#define RSHR4 0x114 // passes D from L1 quad to L2 quad

template<int C>
__device__ __forceinline__ float qpf(float x) {
    return __int_as_float(__builtin_amdgcn_mov_dpp(__float_as_int(x), C, 0xF, 0xF, true));
}

// Pack tokens (int 0/1) into bitmasks, bit t%64 of word t/64 per row.
__global__ __launch_bounds__(1024) void pack_kernel(const int* __restrict__ toks,
                                                    unsigned long long* __restrict__ packed) {
    const int lane = threadIdx.x & 63;
    const int wid  = threadIdx.x >> 6;
    const long long tb = (long long)blockIdx.x * 4096 + wid * 256;
    unsigned long long w0 = __ballot(toks[tb +   0 + lane] != 0);
    unsigned long long w1 = __ballot(toks[tb +  64 + lane] != 0);
    unsigned long long w2 = __ballot(toks[tb + 128 + lane] != 0);
    unsigned long long w3 = __ballot(toks[tb + 192 + lane] != 0);
    if (lane < 4) {
        unsigned long long v = lane == 0 ? w0 : lane == 1 ? w1 : lane == 2 ? w2 : w3;
        packed[(tb >> 6) + lane] = v;
    }
}

// Iteration tt = t0+ss. L1 lanes -> r1(tt); L2 lanes -> r2(tt-2).
// FIRST (iters 0,1) discards L2's pipeline-fill output.
#define STEP(ss, FIRST, DOSAVE)                                           \
  {                                                                       \
    float c = (w & (1u << (ss))) ? cB : cA;                               \
    float o = __int_as_float(__builtin_amdgcn_mov_dpp(                    \
                  __float_as_int(D), RSHR4, 0xF, 0xF, true));             \
    float init = c + o;                                                   \
    float x1 = qpf<QP1>(s);                                               \
    h2 A = __builtin_amdgcn_cvt_pkrtz(s, x1);                             \
    int Bi = __builtin_amdgcn_mov_dpp(__builtin_bit_cast(int, A),         \
                                      QP2, 0xF, 0xF, true);               \
    h2 Bv = __builtin_bit_cast(h2, Bi);                                   \
    float f = __builtin_amdgcn_fdot2(A, w01, init, false);                \
    f = __builtin_amdgcn_fdot2(Bv, w23, f, false);                        \
    float Dn = __builtin_amdgcn_fdot2(A, u01, cD, false);                 \
    Dn = __builtin_amdgcn_fdot2(Bv, u23, Dn, false);                      \
    float e = __builtin_amdgcn_exp2f(f);                                  \
    float r = __builtin_amdgcn_rcpf(e + 1.0f);                            \
    if (DOSAVE) save = ((ss) == lmt2) ? r : save;                         \
    s = (FIRST) ? (isL2 ? r2i : r) : r;                                   \
    D = Dn;                                                               \
  }

__global__ __launch_bounds__(64) void rnn_kernel(
    const unsigned* __restrict__ packed,   // [B][T/32]
    const int* __restrict__ lengths,
    const float* __restrict__ W_ih0, const float* __restrict__ W_hh0,
    const float* __restrict__ b_ih0, const float* __restrict__ b_hh0,
    const float* __restrict__ W_ih1, const float* __restrict__ W_hh1,
    const float* __restrict__ b_ih1, const float* __restrict__ b_hh1,
    const float* __restrict__ h0,
    float* __restrict__ out, int T)
{
    const int lane = threadIdx.x;      // 0..63
    const int g    = lane >> 3;        // element within wave, 0..7
    const int hh   = lane & 7;
    const bool isL2 = (hh & 4) != 0;   // lanes 4-7 of each octet = layer 2
    const int i    = hh & 3;           // component / row 0..3
    const int b    = blockIdx.x * 8 + g;
    const int Tw   = T >> 5;

    const float K  = 2.8853900817779268f;   // 2*log2(e)
    const float NK = -2.0f * K;

    // f32 z-space constants (exact rowsums of the ORIGINAL weights)
    float rs0 = W_hh0[i*4+0] + W_hh0[i*4+1] + W_hh0[i*4+2] + W_hh0[i*4+3];
    float cb0 = b_ih0[i] + b_hh0[i] + rs0;
    float C0  = K * (W_ih0[i*2+0] + cb0);
    float C1  = K * (W_ih0[i*2+1] + cb0);
    float rsA = W_ih1[i*4+0] + W_ih1[i*4+1] + W_ih1[i*4+2] + W_ih1[i*4+3];
    float rsH = W_hh1[i*4+0] + W_hh1[i*4+1] + W_hh1[i*4+2] + W_hh1[i*4+3];
    float C2  = K * (b_ih1[i] + b_hh1[i] + rsA + rsH);

    // f16 weight rows (NK scale) + rounding-delta accumulators
    float dO = 0.0f, dU = 0.0f, dH = 0.0f;
    auto cvt = [](float wf, float& dacc) -> __fp16 {
        __fp16 hw = (__fp16)wf;
        dacc += (wf - (float)hw);
        return hw;
    };
    h2 a01 = { cvt(NK*W_hh0[i*4 + i],     dO), cvt(NK*W_hh0[i*4 + (i^1)], dO) };
    h2 a23 = { cvt(NK*W_hh0[i*4 + (i^2)], dO), cvt(NK*W_hh0[i*4 + (i^3)], dO) };
    h2 b01 = { cvt(NK*W_ih1[i*4 + i],     dU), cvt(NK*W_ih1[i*4 + (i^1)], dU) };
    h2 b23 = { cvt(NK*W_ih1[i*4 + (i^2)], dU), cvt(NK*W_ih1[i*4 + (i^3)], dU) };
    h2 c01 = { cvt(NK*W_hh1[i*4 + i],     dH), cvt(NK*W_hh1[i*4 + (i^1)], dH) };
    h2 c23 = { cvt(NK*W_hh1[i*4 + (i^2)], dH), cvt(NK*W_hh1[i*4 + (i^3)], dH) };

    h2 w01, w23, u01, u23;
    float cA, cB, cD, s;
    if (!isL2) {
        w01 = a01; w23 = a23;          // own recurrence: W_hh0 row i
        u01 = b01; u23 = b23;          // aux dot: W_ih1 row i (for L2 lane i+4)
        cA = C0 + 0.5f * dO;           // token constants + f16 compensation
        cB = C1 + 0.5f * dO;
        cD = C2 + 0.5f * (dU + dH);    // L2's full z-constant lives in D's base
        s  = fmaf(-0.5f, h0[i], 0.5f); // r = (1-h)/2
    } else {
        w01 = c01; w23 = c23;          // own recurrence: W_hh1 row i
        u01 = (h2){(__fp16)0.0f, (__fp16)0.0f};
        u23 = u01;                     // D stays 0 on L2 lanes (feeds L1's o=0)
        cA = cB = 0.0f;                // L2's init comes entirely via o
        cD = 0.0f;
        s  = fmaf(-0.5f, h0[4 + i], 0.5f);
    }
    const float r2i = fmaf(-0.5f, h0[4 + i], 0.5f);
    float save = r2i;
    float D = 0.0f;
    const int len = lengths[b];

    // wave-wide max length (len uniform within each octet) -> uniform bound
    int wmax = len;
    #pragma unroll
    for (int off = 8; off <= 32; off <<= 1) {
        int o2 = __shfl_xor(wmax, off, 64);
        wmax = wmax > o2 ? wmax : o2;
    }
    wmax = __builtin_amdgcn_readfirstlane(wmax);

    const unsigned* row = packed + (size_t)b * Tw;
    unsigned wcur  = row[0];
    unsigned wnext = row[1 < Tw ? 1 : Tw - 1];

    int lmt2 = len + 1;   // L2 emits r2(len-1) at iteration len+1

    // block 0: iters 0,1 are pipeline fill (L2 output discarded); save-enabled.
    {
        unsigned w = wcur;
        wcur  = wnext;
        wnext = row[2 < Tw ? 2 : Tw - 1];
        STEP(0, true, true)
        STEP(1, true, true)
        #pragma unroll
        for (int ss = 2; ss < 32; ++ss) {
            STEP(ss, false, true)
        }
        lmt2 -= 32;
    }
    // need iterations through wmax+1
    for (int t0 = 32; t0 <= wmax + 1; t0 += 32) {
        unsigned w = wcur;
        wcur = wnext;
        int nidx = (t0 >> 5) + 2;
        wnext = row[nidx < Tw ? nidx : Tw - 1];
        if (__any((unsigned)lmt2 < 32u)) {
            #pragma unroll
            for (int ss = 0; ss < 32; ++ss) {
                STEP(ss, false, true)
            }
        } else {
            #pragma unroll
            for (int ss = 0; ss < 32; ++ss) {
                STEP(ss, false, false)
            }
        }
        lmt2 -= 32;
    }

    if (isL2) out[b * 4 + i] = fmaf(-2.0f, save, 1.0f);
}

extern "C" void kernel_launch(void* const* d_in, const int* in_sizes, int n_in,
                              void* d_out, int out_size, void* d_ws, size_t ws_size,
                              hipStream_t stream) {
    const int*   tokens  = (const int*)d_in[0];
    const int*   lengths = (const int*)d_in[1];
    const float* W_ih0   = (const float*)d_in[2];
    const float* W_hh0   = (const float*)d_in[3];
    const float* b_ih0   = (const float*)d_in[4];
    const float* b_hh0   = (const float*)d_in[5];
    const float* W_ih1   = (const float*)d_in[6];
    const float* W_hh1   = (const float*)d_in[7];
    const float* b_ih1   = (const float*)d_in[8];
    const float* b_hh1   = (const float*)d_in[9];
    const float* h0      = (const float*)d_in[10];
    float* out = (float*)d_out;

    const int B = in_sizes[1];
    const int T = in_sizes[0] / B;

    unsigned long long* packed = (unsigned long long*)d_ws;  // B*T/8 bytes

    pack_kernel<<<(B * T) / 4096, 1024, 0, stream>>>(tokens, packed);
    rnn_kernel<<<B / 8, 64, 0, stream>>>((const unsigned*)packed, lengths,
        W_ih0, W_hh0, b_ih0, b_hh0, W_ih1, W_hh1, b_ih1, b_hh1, h0, out, T);
}